// Round 6
// baseline (16676.204 us; speedup 1.0000x reference)
//
#include <hip/hip_runtime.h>

typedef unsigned short u16;
typedef unsigned int u32;
typedef unsigned long long u64;
typedef __attribute__((ext_vector_type(8))) short bf16x8;
typedef __attribute__((ext_vector_type(4))) float f32x4;

__device__ __forceinline__ float b2f(u16 x) {
  union { u32 u; float f; } c; c.u = ((u32)x) << 16; return c.f;
}
__device__ __forceinline__ u16 f2b(float f) {
  union { float f; u32 u; } c; c.f = f;
  u32 u = c.u;
  return (u16)((u + 0x7FFFu + ((u >> 16) & 1u)) >> 16);
}
__device__ __forceinline__ float sigf(float x) { return 1.f / (1.f + __expf(-x)); }
__device__ __forceinline__ float tanhfast(float x) {
  float e = __expf(2.f * x);
  return 1.f - 2.f / (e + 1.f);
}
__device__ __forceinline__ float clampf(float x, float b) {
  return fminf(fmaxf(x, -b), b);
}
__device__ __forceinline__ float loadin(const void* p, long i, u32 isf32) {
  return isf32 ? ((const float*)p)[i] : b2f(((const u16*)p)[i]);
}
// L2-bypassing coherent read (straight from coherence point)
__device__ __forceinline__ u32 l3_load(const u32* p) {
  u32 v;
  asm volatile("global_load_dword %0, %1, off sc0 sc1\n\ts_waitcnt vmcnt(0)"
               : "=v"(v) : "v"(p) : "memory");
  return v;
}
// Write-through store (never lingers dirty in local L2)
__device__ __forceinline__ void l3_store(u32* p, u32 v) {
  asm volatile("global_store_dword %0, %1, off sc0 sc1" :: "v"(p), "v"(v) : "memory");
}
__device__ __forceinline__ void vm_drain() {
  asm volatile("s_waitcnt vmcnt(0)" ::: "memory");
}

// h storage layout (per layer): hsT[t][w][b][j], u16 index =
//   t*32768 + w*512 + b*8 + j     (w: 64 col-blocks, b: 64 batch, j: 8 cols)
// Producer WG w writes 256 consecutive u32 per step (16 full 64B lines).

// ---------------------------------------------------------------------------
__global__ __launch_bounds__(256) void detect_kernel(const u16* __restrict__ bih0,
                                                     u32* __restrict__ flag) {
  __shared__ u32 cnts[2];
  if (threadIdx.x < 2) cnts[threadIdx.x] = 0;
  __syncthreads();
  u32 huge = 0, zeros = 0;
  for (int i = threadIdx.x; i < 2048; i += 256) {
    u16 v = bih0[i];
    u32 e = (v >> 7) & 0xFFu;
    if (e >= 0xC0u) huge++;
    if (v == 0) zeros++;
  }
  atomicAdd(&cnts[0], huge);
  atomicAdd(&cnts[1], zeros);
  __syncthreads();
  if (threadIdx.x == 0) flag[0] = (cnts[0] >= 8u || cnts[1] >= 600u) ? 1u : 0u;
}

// ---------------------------------------------------------------------------
__global__ __launch_bounds__(256) void prep_kernel(
    const void* __restrict__ Wih0, const void* __restrict__ Whh0,
    const void* __restrict__ bih0, const void* __restrict__ bhh0,
    const void* __restrict__ Wih1, const void* __restrict__ Whh1,
    const void* __restrict__ bih1, const void* __restrict__ bhh1,
    const void* __restrict__ W1, const void* __restrict__ b1,
    const void* __restrict__ W2, const void* __restrict__ b2,
    const void* __restrict__ Wf, const void* __restrict__ bfv,
    u16* __restrict__ Wcat0, u16* __restrict__ Wcat1,
    float* __restrict__ biasR0, float* __restrict__ biasR1,
    u16* __restrict__ W1c, float* __restrict__ b1c,
    float* __restrict__ W2c, float* __restrict__ b2c,
    float* __restrict__ Wfc, float* __restrict__ bfc,
    const u32* __restrict__ flag)
{
  const u32 isf32 = flag[0];
  const int gid = blockIdx.x * 256 + threadIdx.x;
  const int gsz = gridDim.x * 256;
  for (int i = gid; i < 2048 * 832; i += gsz) {
    int np = i / 832, k = i - np * 832;
    int g = np & 3, j = np >> 2;
    long orig = g * 512 + j;
    u16 v;
    if (k < 320) v = (k < 300) ? f2b(loadin(Wih0, orig * 300 + k, isf32)) : (u16)0;
    else         v = f2b(loadin(Whh0, orig * 512 + (k - 320), isf32));
    Wcat0[i] = v;
  }
  for (int i = gid; i < 2048 * 1024; i += gsz) {
    int np = i >> 10, k = i & 1023;
    int g = np & 3, j = np >> 2;
    long orig = g * 512 + j;
    Wcat1[i] = (k < 512) ? f2b(loadin(Wih1, orig * 512 + k, isf32))
                         : f2b(loadin(Whh1, orig * 512 + (k - 512), isf32));
  }
  for (int i = gid; i < 2048; i += gsz) {
    int g = i & 3, j = i >> 2;
    long orig = g * 512 + j;
    biasR0[i] = loadin(bih0, orig, isf32) + loadin(bhh0, orig, isf32);
    biasR1[i] = loadin(bih1, orig, isf32) + loadin(bhh1, orig, isf32);
  }
  for (int i = gid; i < 256 * 1024; i += gsz) W1c[i] = f2b(loadin(W1, i, isf32));
  for (int i = gid; i < 256; i += gsz) {
    b1c[i] = loadin(b1, i, isf32);
    W2c[i] = loadin(W2, i, isf32);
  }
  for (int i = gid; i < 1024; i += gsz) Wfc[i] = loadin(Wf, i, isf32);
  if (gid == 0) {
    b2c[0] = loadin(b2, 0, isf32);
    bfc[0] = loadin(bfv, 0, isf32);
  }
}

// ---------------------------------------------------------------------------
__global__ __launch_bounds__(256) void gather_kernel(
    const int* __restrict__ xi, const void* __restrict__ embed,
    u16* __restrict__ xpad, const u32* __restrict__ flag)
{
  const u32 isf32 = flag[0];
  const int r = blockIdx.x * 4 + (threadIdx.x >> 6);
  const int lane = threadIdx.x & 63;
  const int b = r & 63, s = r >> 6;
  const int idx = xi[b * 1024 + s];
  u16* drow = xpad + (u64)r * 320;
  if (!isf32) {
    const u32* src = (const u32*)((const u16*)embed + (u64)idx * 300);
    u32* dst = (u32*)drow;
    for (int c = lane; c < 150; c += 64) dst[c] = src[c];
  } else {
    const float* src = (const float*)embed + (u64)idx * 300;
    for (int c = lane; c < 300; c += 64) drow[c] = f2b(src[c]);
  }
  for (int c = 300 + lane; c < 320; c += 64) drow[c] = 0;
}

// ---------------------------------------------------------------------------
// Fused persistent 2-layer LSTM. 128 WGs: 0-63 layer0, 64-127 layer1 (lag 1).
// Flags: one per WG per layer, each on its OWN 64B line (stride 16 dwords)
// -> poll fan-out spread across L3 slices. h in hsT layout -> producer
// writes 16 full lines/step (no partial-line write amplification).
// ---------------------------------------------------------------------------
__global__ __launch_bounds__(256, 1) void lstm_fused(
    const u16* __restrict__ xpad,
    const u16* __restrict__ Wcat0, const float* __restrict__ biasR0,
    const u16* __restrict__ Wcat1, const float* __restrict__ biasR1,
    u16* __restrict__ h0sT, u16* __restrict__ h1sT,
    u32* __restrict__ flags0, u32* __restrict__ flags1, int S)
{
  __shared__ __align__(16) u16 ldsW[32 * 1032];
  __shared__ __align__(16) u16 ldsH[64 * 520];
  __shared__ float ldsZ[64 * 33];
  __shared__ float ldsC[512];

  const int layer = blockIdx.x >> 6;
  const int w = blockIdx.x & 63;
  const int KX = layer ? 512 : 320;
  const u16* Wcat = layer ? Wcat1 : Wcat0;
  const float* biasR = layer ? biasR1 : biasR0;
  u16* hs = layer ? h1sT : h0sT;
  u32* fown = layer ? flags1 : flags0;

  const int tid = threadIdx.x;
  const int lane = tid & 63;
  const int wv = tid >> 6;
  const int Kt = KX + 512;
  const int PW = Kt + 8;
  const int nu32 = Kt >> 1;

  {   // weight slice rows w*32..w*32+31 -> LDS (one-time)
    const u32* src = (const u32*)Wcat;
    u32* dst = (u32*)ldsW;
    const int pw2 = PW >> 1;
    for (int i = tid; i < 32 * nu32; i += 256) {
      int r = i / nu32, c = i - r * nu32;
      dst[r * pw2 + c] = src[(u64)(w * 32 + r) * nu32 + c];
    }
  }
  for (int i = tid; i < 512; i += 256) ldsC[i] = 0.f;
  __syncthreads();

  const int nksX = KX >> 5;
  const int lrow = lane & 15;
  const int kq = lane >> 4;

  for (int t = 0; t < S; ++t) {
    f32x4 acc0 = {0.f, 0.f, 0.f, 0.f};
    f32x4 acc1 = {0.f, 0.f, 0.f, 0.f};

    // ---- layer-1 input gate: h0sT tile t must be complete
    if (layer) {
      if (wv == 0) {
        const u32* fp = flags0 + lane * 16;
        const u32 target = (u32)(t + 1);
        while (true) {
          u32 v = l3_load(fp);
          if (__all((int)(v >= target))) break;
          __builtin_amdgcn_s_sleep(2);
        }
      }
      __syncthreads();
    }

    // ---- phase 0: x-part staging + MFMA
    if (layer == 0) {
      const u64* src = (const u64*)xpad + (u64)t * 5120;   // 64 rows * 80 u64
      u64* dst = (u64*)ldsH;
      for (int i = tid; i < 5120; i += 256) {
        int r = i / 80, c = i - r * 80;
        dst[r * 130 + c] = src[i];
      }
    } else {
      const u64* src = (const u64*)h0sT + (u64)t * 8192;   // hsT tile, contiguous
      u64* dst = (u64*)ldsH;
      for (int i = tid; i < 8192; i += 256) {
        int wp = i >> 7, r = (i >> 1) & 63, half = i & 1;
        dst[r * 130 + wp * 2 + half] = src[i];
      }
    }
    __syncthreads();
    for (int ks = 0; ks < nksX; ++ks) {
      int k = ks * 32 + kq * 8;
      bf16x8 a  = *(const bf16x8*)&ldsH[(wv * 16 + lrow) * 520 + k];
      bf16x8 b0 = *(const bf16x8*)&ldsW[lrow * PW + k];
      bf16x8 b1 = *(const bf16x8*)&ldsW[(16 + lrow) * PW + k];
      acc0 = __builtin_amdgcn_mfma_f32_16x16x32_bf16(a, b0, acc0, 0, 0, 0);
      acc1 = __builtin_amdgcn_mfma_f32_16x16x32_bf16(a, b1, acc1, 0, 0, 0);
    }

    // ---- phase 1: recurrent part (own layer step t-1 complete)
    if (t > 0) {
      __syncthreads();
      if (wv == 0) {
        const u32* fp = fown + lane * 16;
        const u32 target = (u32)t;
        while (true) {
          u32 v = l3_load(fp);
          if (__all((int)(v >= target))) break;
          __builtin_amdgcn_s_sleep(2);
        }
      }
      __syncthreads();
      {
        const u64* src = (const u64*)hs + (u64)(t - 1) * 8192;
        u64* dst = (u64*)ldsH;
        for (int i = tid; i < 8192; i += 256) {
          int wp = i >> 7, r = (i >> 1) & 63, half = i & 1;
          dst[r * 130 + wp * 2 + half] = src[i];
        }
      }
      __syncthreads();
      for (int ks = 0; ks < 16; ++ks) {
        int k = ks * 32 + kq * 8;
        bf16x8 a  = *(const bf16x8*)&ldsH[(wv * 16 + lrow) * 520 + k];
        bf16x8 b0 = *(const bf16x8*)&ldsW[lrow * PW + KX + k];
        bf16x8 b1 = *(const bf16x8*)&ldsW[(16 + lrow) * PW + KX + k];
        acc0 = __builtin_amdgcn_mfma_f32_16x16x32_bf16(a, b0, acc0, 0, 0, 0);
        acc1 = __builtin_amdgcn_mfma_f32_16x16x32_bf16(a, b1, acc1, 0, 0, 0);
      }
    }

    // ---- z tiles -> LDS (C layout: col=lane&15, row=quad*4+reg)
    {
      int col = lane & 15, q = lane >> 4;
#pragma unroll
      for (int r = 0; r < 4; ++r) {
        int m = wv * 16 + q * 4 + r;
        ldsZ[m * 33 + col] = acc0[r];
        ldsZ[m * 33 + 16 + col] = acc1[r];
      }
    }
    __syncthreads();

    // ---- gates + contiguous full-line h store
    {
      int b = tid >> 2;
      int j0 = (tid & 3) * 2;
      float hv[2];
#pragma unroll
      for (int q2 = 0; q2 < 2; ++q2) {
        int jl = j0 + q2;
        int cb = jl * 4;
        float zi = clampf(ldsZ[b * 33 + cb + 0] + biasR[w * 32 + cb + 0], 30.f);
        float zf = clampf(ldsZ[b * 33 + cb + 1] + biasR[w * 32 + cb + 1], 30.f);
        float zg = clampf(ldsZ[b * 33 + cb + 2] + biasR[w * 32 + cb + 2], 30.f);
        float zo = clampf(ldsZ[b * 33 + cb + 3] + biasR[w * 32 + cb + 3], 30.f);
        float co = ldsC[b * 8 + jl];
        float cn = clampf(sigf(zf) * co + sigf(zi) * tanhfast(zg), 64.f);
        ldsC[b * 8 + jl] = cn;
        hv[q2] = clampf(sigf(zo) * tanhfast(cn), 1.f);
      }
      u32 packed = (u32)f2b(hv[0]) | ((u32)f2b(hv[1]) << 16);
      // hsT u32 index: t*16384 + w*256 + tid  (tid == b*4 + j0/2)
      u32* hdst = (u32*)hs + (u64)t * 16384 + w * 256 + tid;
      l3_store(hdst, packed);
      vm_drain();
    }
    __syncthreads();            // all threads' h stores at coherence point
    if (tid == 0) l3_store(fown + w * 16, (u32)(t + 1));
  }
}

// ---------------------------------------------------------------------------
// gemm over hsT A: C[M=65536,N=256](bf16) = A_hsT @ B[N,K=512]^T. 128x128.
// A(m,k) u16 idx = (m>>6)*32768 + (k>>3)*512 + (m&63)*8 + (k&7)
// ---------------------------------------------------------------------------
__global__ __launch_bounds__(256, 1) void gemm_hA(
    const u16* __restrict__ A,
    const u16* __restrict__ B, int ldb,
    u16* __restrict__ C, int ldc, int K)
{
  __shared__ __align__(16) u16 As[128 * 40];
  __shared__ __align__(16) u16 Bs[128 * 40];
  const int tid = threadIdx.x;
  const int bn = blockIdx.x * 128;
  const int bm = blockIdx.y * 128;
  const int lane = tid & 63;
  const int wv = tid >> 6;
  const int mh = wv >> 1, nh = wv & 1;
  const int lrow = lane & 15, kq = lane >> 4;
  const int sr = tid >> 1, sh = (tid & 1) * 16;
  const int m_ = bm + sr, s_ = m_ >> 6, bb = m_ & 63;
  f32x4 acc[4][4];
#pragma unroll
  for (int i = 0; i < 4; ++i)
#pragma unroll
    for (int j = 0; j < 4; ++j) acc[i][j] = {0.f, 0.f, 0.f, 0.f};

  for (int k0 = 0; k0 < K; k0 += 32) {
    const u16* ap = A + (u64)s_ * 32768 + (u64)((k0 + sh) >> 3) * 512 + bb * 8;
    *(bf16x8*)&As[sr * 40 + sh]     = *(const bf16x8*)ap;
    *(bf16x8*)&As[sr * 40 + sh + 8] = *(const bf16x8*)(ap + 512);
    *(bf16x8*)&Bs[sr * 40 + sh]     = *(const bf16x8*)(B + (u64)(bn + sr) * ldb + k0 + sh);
    *(bf16x8*)&Bs[sr * 40 + sh + 8] = *(const bf16x8*)(B + (u64)(bn + sr) * ldb + k0 + sh + 8);
    __syncthreads();
    bf16x8 af[4], bfr[4];
#pragma unroll
    for (int mt = 0; mt < 4; ++mt)
      af[mt] = *(const bf16x8*)&As[(mh * 64 + mt * 16 + lrow) * 40 + kq * 8];
#pragma unroll
    for (int nt = 0; nt < 4; ++nt)
      bfr[nt] = *(const bf16x8*)&Bs[(nh * 64 + nt * 16 + lrow) * 40 + kq * 8];
#pragma unroll
    for (int mt = 0; mt < 4; ++mt)
#pragma unroll
      for (int nt = 0; nt < 4; ++nt)
        acc[mt][nt] = __builtin_amdgcn_mfma_f32_16x16x32_bf16(af[mt], bfr[nt], acc[mt][nt], 0, 0, 0);
    __syncthreads();
  }
#pragma unroll
  for (int mt = 0; mt < 4; ++mt)
#pragma unroll
    for (int nt = 0; nt < 4; ++nt)
#pragma unroll
      for (int r = 0; r < 4; ++r) {
        int m = bm + mh * 64 + mt * 16 + kq * 4 + r;
        int n = bn + nh * 64 + nt * 16 + lrow;
        C[(u64)m * ldc + n] = f2b(clampf(acc[mt][nt][r], 60.f));
      }
}

// ---------------------------------------------------------------------------
// part1[b][l] = b1[l] + sum_k h_N[b][k] * W1[l][k]   (h_N from h1sT t=1023)
// ---------------------------------------------------------------------------
__global__ __launch_bounds__(256) void part1_kernel(
    const u16* __restrict__ h1sT, const u16* __restrict__ W1c,
    const float* __restrict__ b1c, float* __restrict__ part1)
{
  __shared__ float hN[512];
  const int b = blockIdx.x;
  const int l = threadIdx.x;
  for (int i = l; i < 512; i += 256)
    hN[i] = b2f(h1sT[(u64)1023 * 32768 + (i >> 3) * 512 + b * 8 + (i & 7)]);
  __syncthreads();
  const u16* wrow = W1c + (u64)l * 1024;
  float acc = b1c[l];
  for (int k = 0; k < 512; ++k) acc += hN[k] * b2f(wrow[k]);
  part1[b * 256 + l] = clampf(acc, 60.f);
}

// ---------------------------------------------------------------------------
// e[b][s] = sum_l tanh(part1[b][l] + part2[m][l]) * W2[l] + b2,  m = s*64+b
// ---------------------------------------------------------------------------
__global__ __launch_bounds__(256) void escore_kernel(
    const float* __restrict__ part1, const u16* __restrict__ part2,
    const float* __restrict__ W2c, const float* __restrict__ b2c,
    float* __restrict__ e)
{
  const int m = blockIdx.x * 4 + (threadIdx.x >> 6);
  const int lane = threadIdx.x & 63;
  const int b = m & 63, s = m >> 6;
  float acc = 0.f;
  for (int l = lane; l < 256; l += 64)
    acc += tanhfast(part1[b * 256 + l] + b2f(part2[(u64)m * 256 + l])) * W2c[l];
#pragma unroll
  for (int off = 32; off; off >>= 1) acc += __shfl_down(acc, off, 64);
  if (lane == 0) e[b * 1024 + s] = clampf(acc + b2c[0], 60.f);
}

// ---------------------------------------------------------------------------
// finish: softmax, attn write, context (h1sT layout), sigmoid.
// ---------------------------------------------------------------------------
__global__ __launch_bounds__(256) void finish_kernel(
    const float* __restrict__ e, const u16* __restrict__ h1sT,
    const float* __restrict__ Wfc, const float* __restrict__ bfc,
    void* __restrict__ dout, const u32* __restrict__ flag)
{
  __shared__ float sw[1024];
  __shared__ float red[4];
  __shared__ float hN[512];
  const u32 isf32 = flag[0];
  const int b = blockIdx.x;
  const int tid = threadIdx.x;
  const int lane = tid & 63, wv = tid >> 6;

  float mx = -1e30f;
  for (int s = tid; s < 1024; s += 256) {
    float v = e[b * 1024 + s];
    sw[s] = v;
    mx = fmaxf(mx, v);
  }
#pragma unroll
  for (int off = 1; off < 64; off <<= 1) mx = fmaxf(mx, __shfl_xor(mx, off, 64));
  if (lane == 0) red[wv] = mx;
  __syncthreads();
  mx = fmaxf(fmaxf(red[0], red[1]), fmaxf(red[2], red[3]));
  __syncthreads();

  float sum = 0.f;
  for (int s = tid; s < 1024; s += 256) {
    float p = __expf(sw[s] - mx);
    sw[s] = p;
    sum += p;
  }
#pragma unroll
  for (int off = 1; off < 64; off <<= 1) sum += __shfl_xor(sum, off, 64);
  if (lane == 0) red[wv] = sum;
  __syncthreads();
  sum = red[0] + red[1] + red[2] + red[3];
  float inv = 1.f / sum;
  for (int s = tid; s < 1024; s += 256) {
    float wn = sw[s] * inv;
    sw[s] = wn;
    if (isf32) ((float*)dout)[b * 1024 + s] = wn;
    else       ((u16*)dout)[b * 1024 + s] = f2b(wn);
  }
  for (int i = tid; i < 512; i += 256)
    hN[i] = b2f(h1sT[(u64)1023 * 32768 + (i >> 3) * 512 + b * 8 + (i & 7)]);
  __syncthreads();

  const int c0 = tid, c1 = tid + 256;
  const u64 off0 = (u64)(c0 >> 3) * 512 + b * 8 + (c0 & 7);
  const u64 off1 = (u64)(c1 >> 3) * 512 + b * 8 + (c1 & 7);
  float a0 = 0.f, a1 = 0.f;
  for (int s = 0; s < 1024; ++s) {
    const u16* hr = h1sT + (u64)s * 32768;
    float wn = sw[s];
    a0 += wn * b2f(hr[off0]);
    a1 += wn * b2f(hr[off1]);
  }
  float part = a0 * Wfc[c0] + a1 * Wfc[c1] + hN[c0] * Wfc[512 + c0] + hN[c1] * Wfc[512 + c1];
#pragma unroll
  for (int off = 1; off < 64; off <<= 1) part += __shfl_xor(part, off, 64);
  __syncthreads();
  if (lane == 0) red[wv] = part;
  __syncthreads();
  if (tid == 0) {
    float tot = clampf(red[0] + red[1] + red[2] + red[3] + bfc[0], 30.f);
    float o = sigf(tot);
    if (isf32) ((float*)dout)[65536 + b] = o;
    else       ((u16*)dout)[65536 + b] = f2b(o);
  }
}

// ---------------------------------------------------------------------------
extern "C" void kernel_launch(void* const* d_in, const int* in_sizes, int n_in,
                              void* d_out, int out_size, void* d_ws, size_t ws_size,
                              hipStream_t stream) {
  const int* x_index = (const int*)d_in[0];
  const void* embed = d_in[1];
  const void* Wih0 = d_in[2];
  const void* Whh0 = d_in[3];
  const void* bih0 = d_in[4];
  const void* bhh0 = d_in[5];
  const void* Wih1 = d_in[6];
  const void* Whh1 = d_in[7];
  const void* bih1 = d_in[8];
  const void* bhh1 = d_in[9];
  const void* W1 = d_in[10];
  const void* b1 = d_in[11];
  const void* W2 = d_in[12];
  const void* b2 = d_in[13];
  const void* Wf = d_in[14];
  const void* bfv = d_in[15];

  char* ws = (char*)d_ws;
  size_t off = 0;
  auto alloc = [&](size_t bytes) -> char* {
    char* p = ws + off;
    off += (bytes + 255) & ~(size_t)255;
    return p;
  };
  u32* flags0    = (u32*)alloc(64 * 16 * 4);   // one flag per 64B line
  u32* flags1    = (u32*)alloc(64 * 16 * 4);
  u32* flag      = (u32*)alloc(256);
  float* biasR0  = (float*)alloc(2048 * 4);
  float* biasR1  = (float*)alloc(2048 * 4);
  float* part1   = (float*)alloc(64 * 256 * 4);
  float* e       = (float*)alloc(64 * 1024 * 4);
  float* b1c     = (float*)alloc(256 * 4);
  float* W2c     = (float*)alloc(256 * 4);
  float* b2c     = (float*)alloc(16);
  float* Wfc     = (float*)alloc(1024 * 4);
  float* bfc     = (float*)alloc(16);
  u16* W1c       = (u16*)alloc((size_t)256 * 1024 * 2);
  u16* Wcat0     = (u16*)alloc((size_t)2048 * 832 * 2);
  u16* Wcat1     = (u16*)alloc((size_t)2048 * 1024 * 2);
  u16* xpad      = (u16*)alloc((size_t)65536 * 320 * 2);
  u16* h0sT      = (u16*)alloc((size_t)65536 * 512 * 2);
  u16* h1sT      = (u16*)alloc((size_t)65536 * 512 * 2);
  u16* part2     = (u16*)alloc((size_t)65536 * 256 * 2);
  (void)ws_size; (void)in_sizes; (void)n_in; (void)out_size;

  hipMemsetAsync(flags0, 0, 64 * 16 * 4 * 2, stream);  // flags0 + flags1
  hipLaunchKernelGGL(detect_kernel, dim3(1), dim3(256), 0, stream,
                     (const u16*)bih0, flag);
  hipLaunchKernelGGL(prep_kernel, dim3(512), dim3(256), 0, stream,
                     Wih0, Whh0, bih0, bhh0, Wih1, Whh1, bih1, bhh1,
                     W1, b1, W2, b2, Wf, bfv,
                     Wcat0, Wcat1, biasR0, biasR1,
                     W1c, b1c, W2c, b2c, Wfc, bfc, flag);
  hipLaunchKernelGGL(gather_kernel, dim3(16384), dim3(256), 0, stream,
                     x_index, embed, xpad, flag);
  hipLaunchKernelGGL(lstm_fused, dim3(128), dim3(256), 0, stream,
                     xpad, Wcat0, biasR0, Wcat1, biasR1,
                     h0sT, h1sT, flags0, flags1, 1024);
  hipLaunchKernelGGL(part1_kernel, dim3(64), dim3(256), 0, stream,
                     h1sT, W1c, b1c, part1);
  hipLaunchKernelGGL(gemm_hA, dim3(2, 512), dim3(256), 0, stream,
                     h1sT, W1c + 512, 1024, part2, 256, 512);
  hipLaunchKernelGGL(escore_kernel, dim3(16384), dim3(256), 0, stream,
                     part1, part2, W2c, b2c, e);
  hipLaunchKernelGGL(finish_kernel, dim3(64), dim3(256), 0, stream,
                     e, h1sT, Wfc, bfc, d_out, flag);
}

// Round 8
// 5599.854 us; speedup vs baseline: 2.9780x; 2.9780x over previous
//
#include <hip/hip_runtime.h>

typedef unsigned short u16;
typedef unsigned int u32;
typedef unsigned long long u64;
typedef __attribute__((ext_vector_type(8))) short bf16x8;
typedef __attribute__((ext_vector_type(4))) float f32x4;

__device__ __forceinline__ float b2f(u16 x) {
  union { u32 u; float f; } c; c.u = ((u32)x) << 16; return c.f;
}
__device__ __forceinline__ u16 f2b(float f) {
  union { float f; u32 u; } c; c.f = f;
  u32 u = c.u;
  return (u16)((u + 0x7FFFu + ((u >> 16) & 1u)) >> 16);
}
__device__ __forceinline__ float sigf(float x) { return 1.f / (1.f + __expf(-x)); }
__device__ __forceinline__ float tanhfast(float x) {
  float e = __expf(2.f * x);
  return 1.f - 2.f / (e + 1.f);
}
__device__ __forceinline__ float clampf(float x, float b) {
  return fminf(fmaxf(x, -b), b);
}
__device__ __forceinline__ float loadin(const void* p, long i, u32 isf32) {
  return isf32 ? ((const float*)p)[i] : b2f(((const u16*)p)[i]);
}
// L2-bypassing coherent read (straight from coherence point)
__device__ __forceinline__ u32 l3_load(const u32* p) {
  u32 v;
  asm volatile("global_load_dword %0, %1, off sc0 sc1\n\ts_waitcnt vmcnt(0)"
               : "=v"(v) : "v"(p) : "memory");
  return v;
}
// Write-through store (never lingers dirty in local L2)
__device__ __forceinline__ void l3_store(u32* p, u32 v) {
  asm volatile("global_store_dword %0, %1, off sc0 sc1" :: "v"(p), "v"(v) : "memory");
}
__device__ __forceinline__ void vm_drain() {
  asm volatile("s_waitcnt vmcnt(0)" ::: "memory");
}

// Latency-parallel staging: N 16B chunks per thread, ALL loads issued before
// any LDS store -> single latency exposure instead of N/unroll batches.
template <int N>
__device__ __forceinline__ void stageN(const f32x4* __restrict__ g,
                                       f32x4* __restrict__ l, int tid) {
  f32x4 t[N];
#pragma unroll
  for (int i = 0; i < N; ++i) t[i] = g[i * 256 + tid];
#pragma unroll
  for (int i = 0; i < N; ++i) l[i * 256 + tid] = t[i];
}

// Layouts:
//  hsT[t][w][b][j]  u16 idx = t*32768 + w*512 + b*8 + j   (w=64 col-blocks)
//  xT [s][k8][b][j] u16 idx = s*20480 + k8*512 + b*8 + j  (k8=40 col-blocks)
// Both tiles are contiguous per step -> direct register-batched staging, and
// A-frag reads in LDS are 16B-contiguous per lane (bank-balanced).

// ---------------------------------------------------------------------------
__global__ __launch_bounds__(256) void detect_kernel(const u16* __restrict__ bih0,
                                                     u32* __restrict__ flag) {
  __shared__ u32 cnts[2];
  if (threadIdx.x < 2) cnts[threadIdx.x] = 0;
  __syncthreads();
  u32 huge = 0, zeros = 0;
  for (int i = threadIdx.x; i < 2048; i += 256) {
    u16 v = bih0[i];
    u32 e = (v >> 7) & 0xFFu;
    if (e >= 0xC0u) huge++;
    if (v == 0) zeros++;
  }
  atomicAdd(&cnts[0], huge);
  atomicAdd(&cnts[1], zeros);
  __syncthreads();
  if (threadIdx.x == 0) flag[0] = (cnts[0] >= 8u || cnts[1] >= 600u) ? 1u : 0u;
}

// ---------------------------------------------------------------------------
__global__ __launch_bounds__(256) void prep_kernel(
    const void* __restrict__ Wih0, const void* __restrict__ Whh0,
    const void* __restrict__ bih0, const void* __restrict__ bhh0,
    const void* __restrict__ Wih1, const void* __restrict__ Whh1,
    const void* __restrict__ bih1, const void* __restrict__ bhh1,
    const void* __restrict__ W1, const void* __restrict__ b1,
    const void* __restrict__ W2, const void* __restrict__ b2,
    const void* __restrict__ Wf, const void* __restrict__ bfv,
    u16* __restrict__ Wcat0, u16* __restrict__ Wcat1,
    float* __restrict__ biasR0, float* __restrict__ biasR1,
    u16* __restrict__ W1c, float* __restrict__ b1c,
    float* __restrict__ W2c, float* __restrict__ b2c,
    float* __restrict__ Wfc, float* __restrict__ bfc,
    const u32* __restrict__ flag)
{
  const u32 isf32 = flag[0];
  const int gid = blockIdx.x * 256 + threadIdx.x;
  const int gsz = gridDim.x * 256;
  for (int i = gid; i < 2048 * 832; i += gsz) {
    int np = i / 832, k = i - np * 832;
    int g = np & 3, j = np >> 2;
    long orig = g * 512 + j;
    u16 v;
    if (k < 320) v = (k < 300) ? f2b(loadin(Wih0, orig * 300 + k, isf32)) : (u16)0;
    else         v = f2b(loadin(Whh0, orig * 512 + (k - 320), isf32));
    Wcat0[i] = v;
  }
  for (int i = gid; i < 2048 * 1024; i += gsz) {
    int np = i >> 10, k = i & 1023;
    int g = np & 3, j = np >> 2;
    long orig = g * 512 + j;
    Wcat1[i] = (k < 512) ? f2b(loadin(Wih1, orig * 512 + k, isf32))
                         : f2b(loadin(Whh1, orig * 512 + (k - 512), isf32));
  }
  for (int i = gid; i < 2048; i += gsz) {
    int g = i & 3, j = i >> 2;
    long orig = g * 512 + j;
    biasR0[i] = loadin(bih0, orig, isf32) + loadin(bhh0, orig, isf32);
    biasR1[i] = loadin(bih1, orig, isf32) + loadin(bhh1, orig, isf32);
  }
  for (int i = gid; i < 256 * 1024; i += gsz) W1c[i] = f2b(loadin(W1, i, isf32));
  for (int i = gid; i < 256; i += gsz) {
    b1c[i] = loadin(b1, i, isf32);
    W2c[i] = loadin(W2, i, isf32);
  }
  for (int i = gid; i < 1024; i += gsz) Wfc[i] = loadin(Wf, i, isf32);
  if (gid == 0) {
    b2c[0] = loadin(b2, 0, isf32);
    bfc[0] = loadin(bfv, 0, isf32);
  }
}

// ---------------------------------------------------------------------------
// gather -> xT layout: xT[s][c>>3][b][c&7]
// ---------------------------------------------------------------------------
__global__ __launch_bounds__(256) void gather_kernel(
    const int* __restrict__ xi, const void* __restrict__ embed,
    u16* __restrict__ xT, const u32* __restrict__ flag)
{
  const u32 isf32 = flag[0];
  const int r = blockIdx.x * 4 + (threadIdx.x >> 6);
  const int lane = threadIdx.x & 63;
  const int b = r & 63, s = r >> 6;
  const int idx = xi[b * 1024 + s];
  u16* dst = xT + (u64)s * 20480 + b * 8;
  if (!isf32) {
    const u16* src = (const u16*)embed + (u64)idx * 300;
    for (int c = lane; c < 300; c += 64) dst[(c >> 3) * 512 + (c & 7)] = src[c];
  } else {
    const float* src = (const float*)embed + (u64)idx * 300;
    for (int c = lane; c < 300; c += 64) dst[(c >> 3) * 512 + (c & 7)] = f2b(src[c]);
  }
  for (int c = 300 + lane; c < 320; c += 64) dst[(c >> 3) * 512 + (c & 7)] = 0;
}

// ---------------------------------------------------------------------------
// Fused persistent 2-layer LSTM. 128 WGs: 0-63 layer0, 64-127 layer1 (lag 1).
// All dependency waits at top-of-step; staging via stageN (single latency
// exposure); LDS tiles in T layout (contiguous with global).
// ---------------------------------------------------------------------------
__global__ __launch_bounds__(256, 1) void lstm_fused(
    const u16* __restrict__ xT,
    const u16* __restrict__ Wcat0, const float* __restrict__ biasR0,
    const u16* __restrict__ Wcat1, const float* __restrict__ biasR1,
    u16* __restrict__ h0sT, u16* __restrict__ h1sT,
    u32* __restrict__ flags0, u32* __restrict__ flags1, int S)
{
  __shared__ __align__(16) u16 ldsW[32 * 1032];   // weight slice, padded pitch
  __shared__ __align__(16) u16 ldsHT[32768];      // x/h tile, T layout (64 KB)
  __shared__ float ldsZ[64 * 33];
  __shared__ float ldsC[512];

  const int layer = blockIdx.x >> 6;
  const int w = blockIdx.x & 63;
  const int KX = layer ? 512 : 320;
  const u16* Wcat = layer ? Wcat1 : Wcat0;
  const float* biasR = layer ? biasR1 : biasR0;
  u16* hs = layer ? h1sT : h0sT;
  u32* fown = layer ? flags1 : flags0;

  const int tid = threadIdx.x;
  const int lane = tid & 63;
  const int wv = tid >> 6;
  const int Kt = KX + 512;
  const int PW = Kt + 8;
  const int nu32 = Kt >> 1;

  {   // weight slice rows w*32..w*32+31 -> LDS (one-time)
    const u32* src = (const u32*)Wcat;
    u32* dst = (u32*)ldsW;
    const int pw2 = PW >> 1;
    for (int i = tid; i < 32 * nu32; i += 256) {
      int r = i / nu32, c = i - r * nu32;
      dst[r * pw2 + c] = src[(u64)(w * 32 + r) * nu32 + c];
    }
  }
  for (int i = tid; i < 512; i += 256) ldsC[i] = 0.f;
  __syncthreads();

  const int nksX = KX >> 5;                 // 10 or 16
  const int lrow = lane & 15;
  const int kq = lane >> 4;
  const int arow = (wv * 16 + lrow) * 8;    // A-frag base (b*8) in ldsHT
  f32x4* ldsV = (f32x4*)ldsHT;

  for (int t = 0; t < S; ++t) {
    f32x4 acc0 = {0.f, 0.f, 0.f, 0.f};
    f32x4 acc1 = {0.f, 0.f, 0.f, 0.f};

    // ---- top-of-step waits (monotone flags; earlier is still sufficient)
    if (layer || t > 0) {
      if (wv == 0) {
        if (layer) {
          const u32* fp = flags0 + lane * 16;
          const u32 tgt = (u32)(t + 1);
          while (!__all((int)(l3_load(fp) >= tgt))) __builtin_amdgcn_s_sleep(1);
        }
        if (t > 0) {
          const u32* fp = fown + lane * 16;
          const u32 tgt = (u32)t;
          while (!__all((int)(l3_load(fp) >= tgt))) __builtin_amdgcn_s_sleep(1);
        }
      }
      __syncthreads();
    }

    // ---- phase 0: x-tile stage + MFMA
    if (layer == 0) {
      stageN<10>((const f32x4*)(xT + (u64)t * 20480), ldsV, tid);
    } else {
      stageN<16>((const f32x4*)(h0sT + (u64)t * 32768), ldsV, tid);
    }
    __syncthreads();
    for (int ks = 0; ks < nksX; ++ks) {
      int k = ks * 32 + kq * 8;
      bf16x8 a  = *(const bf16x8*)&ldsHT[(ks * 4 + kq) * 512 + arow];
      bf16x8 b0 = *(const bf16x8*)&ldsW[lrow * PW + k];
      bf16x8 b1 = *(const bf16x8*)&ldsW[(16 + lrow) * PW + k];
      acc0 = __builtin_amdgcn_mfma_f32_16x16x32_bf16(a, b0, acc0, 0, 0, 0);
      acc1 = __builtin_amdgcn_mfma_f32_16x16x32_bf16(a, b1, acc1, 0, 0, 0);
    }

    // ---- phase 1: recurrent tile stage + MFMA
    if (t > 0) {
      __syncthreads();   // all waves done reading x tile from ldsHT
      stageN<16>((const f32x4*)(hs + (u64)(t - 1) * 32768), ldsV, tid);
      __syncthreads();
      for (int ks = 0; ks < 16; ++ks) {
        int k = ks * 32 + kq * 8;
        bf16x8 a  = *(const bf16x8*)&ldsHT[(ks * 4 + kq) * 512 + arow];
        bf16x8 b0 = *(const bf16x8*)&ldsW[lrow * PW + KX + k];
        bf16x8 b1 = *(const bf16x8*)&ldsW[(16 + lrow) * PW + KX + k];
        acc0 = __builtin_amdgcn_mfma_f32_16x16x32_bf16(a, b0, acc0, 0, 0, 0);
        acc1 = __builtin_amdgcn_mfma_f32_16x16x32_bf16(a, b1, acc1, 0, 0, 0);
      }
    }

    // ---- z tiles -> LDS (C layout: col=lane&15, row=quad*4+reg)
    {
      int col = lane & 15, q = lane >> 4;
#pragma unroll
      for (int r = 0; r < 4; ++r) {
        int m = wv * 16 + q * 4 + r;
        ldsZ[m * 33 + col] = acc0[r];
        ldsZ[m * 33 + 16 + col] = acc1[r];
      }
    }
    __syncthreads();

    // ---- gates + contiguous full-line h store
    {
      int b = tid >> 2;
      int j0 = (tid & 3) * 2;
      float hv[2];
#pragma unroll
      for (int q2 = 0; q2 < 2; ++q2) {
        int jl = j0 + q2;
        int cb = jl * 4;
        float zi = clampf(ldsZ[b * 33 + cb + 0] + biasR[w * 32 + cb + 0], 30.f);
        float zf = clampf(ldsZ[b * 33 + cb + 1] + biasR[w * 32 + cb + 1], 30.f);
        float zg = clampf(ldsZ[b * 33 + cb + 2] + biasR[w * 32 + cb + 2], 30.f);
        float zo = clampf(ldsZ[b * 33 + cb + 3] + biasR[w * 32 + cb + 3], 30.f);
        float co = ldsC[b * 8 + jl];
        float cn = clampf(sigf(zf) * co + sigf(zi) * tanhfast(zg), 64.f);
        ldsC[b * 8 + jl] = cn;
        hv[q2] = clampf(sigf(zo) * tanhfast(cn), 1.f);
      }
      u32 packed = (u32)f2b(hv[0]) | ((u32)f2b(hv[1]) << 16);
      u32* hdst = (u32*)hs + (u64)t * 16384 + w * 256 + tid;
      l3_store(hdst, packed);
      vm_drain();
    }
    __syncthreads();            // all threads' h stores at coherence point
    if (tid == 0) l3_store(fown + w * 16, (u32)(t + 1));
  }
}

// ---------------------------------------------------------------------------
// gemm over hsT A: C[M=65536,N=256](bf16) = A_hsT @ B[N,K=512]^T. 128x128.
// ---------------------------------------------------------------------------
__global__ __launch_bounds__(256, 1) void gemm_hA(
    const u16* __restrict__ A,
    const u16* __restrict__ B, int ldb,
    u16* __restrict__ C, int ldc, int K)
{
  __shared__ __align__(16) u16 As[128 * 40];
  __shared__ __align__(16) u16 Bs[128 * 40];
  const int tid = threadIdx.x;
  const int bn = blockIdx.x * 128;
  const int bm = blockIdx.y * 128;
  const int lane = tid & 63;
  const int wv = tid >> 6;
  const int mh = wv >> 1, nh = wv & 1;
  const int lrow = lane & 15, kq = lane >> 4;
  const int sr = tid >> 1, sh = (tid & 1) * 16;
  const int m_ = bm + sr, s_ = m_ >> 6, bb = m_ & 63;
  f32x4 acc[4][4];
#pragma unroll
  for (int i = 0; i < 4; ++i)
#pragma unroll
    for (int j = 0; j < 4; ++j) acc[i][j] = {0.f, 0.f, 0.f, 0.f};

  for (int k0 = 0; k0 < K; k0 += 32) {
    const u16* ap = A + (u64)s_ * 32768 + (u64)((k0 + sh) >> 3) * 512 + bb * 8;
    *(bf16x8*)&As[sr * 40 + sh]     = *(const bf16x8*)ap;
    *(bf16x8*)&As[sr * 40 + sh + 8] = *(const bf16x8*)(ap + 512);
    *(bf16x8*)&Bs[sr * 40 + sh]     = *(const bf16x8*)(B + (u64)(bn + sr) * ldb + k0 + sh);
    *(bf16x8*)&Bs[sr * 40 + sh + 8] = *(const bf16x8*)(B + (u64)(bn + sr) * ldb + k0 + sh + 8);
    __syncthreads();
    bf16x8 af[4], bfr[4];
#pragma unroll
    for (int mt = 0; mt < 4; ++mt)
      af[mt] = *(const bf16x8*)&As[(mh * 64 + mt * 16 + lrow) * 40 + kq * 8];
#pragma unroll
    for (int nt = 0; nt < 4; ++nt)
      bfr[nt] = *(const bf16x8*)&Bs[(nh * 64 + nt * 16 + lrow) * 40 + kq * 8];
#pragma unroll
    for (int mt = 0; mt < 4; ++mt)
#pragma unroll
      for (int nt = 0; nt < 4; ++nt)
        acc[mt][nt] = __builtin_amdgcn_mfma_f32_16x16x32_bf16(af[mt], bfr[nt], acc[mt][nt], 0, 0, 0);
    __syncthreads();
  }
#pragma unroll
  for (int mt = 0; mt < 4; ++mt)
#pragma unroll
    for (int nt = 0; nt < 4; ++nt)
#pragma unroll
      for (int r = 0; r < 4; ++r) {
        int m = bm + mh * 64 + mt * 16 + kq * 4 + r;
        int n = bn + nh * 64 + nt * 16 + lrow;
        C[(u64)m * ldc + n] = f2b(clampf(acc[mt][nt][r], 60.f));
      }
}

// ---------------------------------------------------------------------------
__global__ __launch_bounds__(256) void part1_kernel(
    const u16* __restrict__ h1sT, const u16* __restrict__ W1c,
    const float* __restrict__ b1c, float* __restrict__ part1)
{
  __shared__ float hN[512];
  const int b = blockIdx.x;
  const int l = threadIdx.x;
  for (int i = l; i < 512; i += 256)
    hN[i] = b2f(h1sT[(u64)1023 * 32768 + (i >> 3) * 512 + b * 8 + (i & 7)]);
  __syncthreads();
  const u16* wrow = W1c + (u64)l * 1024;
  float acc = b1c[l];
  for (int k = 0; k < 512; ++k) acc += hN[k] * b2f(wrow[k]);
  part1[b * 256 + l] = clampf(acc, 60.f);
}

// ---------------------------------------------------------------------------
__global__ __launch_bounds__(256) void escore_kernel(
    const float* __restrict__ part1, const u16* __restrict__ part2,
    const float* __restrict__ W2c, const float* __restrict__ b2c,
    float* __restrict__ e)
{
  const int m = blockIdx.x * 4 + (threadIdx.x >> 6);
  const int lane = threadIdx.x & 63;
  const int b = m & 63, s = m >> 6;
  float acc = 0.f;
  for (int l = lane; l < 256; l += 64)
    acc += tanhfast(part1[b * 256 + l] + b2f(part2[(u64)m * 256 + l])) * W2c[l];
#pragma unroll
  for (int off = 32; off; off >>= 1) acc += __shfl_down(acc, off, 64);
  if (lane == 0) e[b * 1024 + s] = clampf(acc + b2c[0], 60.f);
}

// ---------------------------------------------------------------------------
__global__ __launch_bounds__(256) void finish_kernel(
    const float* __restrict__ e, const u16* __restrict__ h1sT,
    const float* __restrict__ Wfc, const float* __restrict__ bfc,
    void* __restrict__ dout, const u32* __restrict__ flag)
{
  __shared__ float sw[1024];
  __shared__ float red[4];
  __shared__ float hN[512];
  const u32 isf32 = flag[0];
  const int b = blockIdx.x;
  const int tid = threadIdx.x;
  const int lane = tid & 63, wv = tid >> 6;

  float mx = -1e30f;
  for (int s = tid; s < 1024; s += 256) {
    float v = e[b * 1024 + s];
    sw[s] = v;
    mx = fmaxf(mx, v);
  }
#pragma unroll
  for (int off = 1; off < 64; off <<= 1) mx = fmaxf(mx, __shfl_xor(mx, off, 64));
  if (lane == 0) red[wv] = mx;
  __syncthreads();
  mx = fmaxf(fmaxf(red[0], red[1]), fmaxf(red[2], red[3]));
  __syncthreads();

  float sum = 0.f;
  for (int s = tid; s < 1024; s += 256) {
    float p = __expf(sw[s] - mx);
    sw[s] = p;
    sum += p;
  }
#pragma unroll
  for (int off = 1; off < 64; off <<= 1) sum += __shfl_xor(sum, off, 64);
  if (lane == 0) red[wv] = sum;
  __syncthreads();
  sum = red[0] + red[1] + red[2] + red[3];
  float inv = 1.f / sum;
  for (int s = tid; s < 1024; s += 256) {
    float wn = sw[s] * inv;
    sw[s] = wn;
    if (isf32) ((float*)dout)[b * 1024 + s] = wn;
    else       ((u16*)dout)[b * 1024 + s] = f2b(wn);
  }
  for (int i = tid; i < 512; i += 256)
    hN[i] = b2f(h1sT[(u64)1023 * 32768 + (i >> 3) * 512 + b * 8 + (i & 7)]);
  __syncthreads();

  const int c0 = tid, c1 = tid + 256;
  const u64 off0 = (u64)(c0 >> 3) * 512 + b * 8 + (c0 & 7);
  const u64 off1 = (u64)(c1 >> 3) * 512 + b * 8 + (c1 & 7);
  float a0 = 0.f, a1 = 0.f;
  for (int s = 0; s < 1024; ++s) {
    const u16* hr = h1sT + (u64)s * 32768;
    float wn = sw[s];
    a0 += wn * b2f(hr[off0]);
    a1 += wn * b2f(hr[off1]);
  }
  float part = a0 * Wfc[c0] + a1 * Wfc[c1] + hN[c0] * Wfc[512 + c0] + hN[c1] * Wfc[512 + c1];
#pragma unroll
  for (int off = 1; off < 64; off <<= 1) part += __shfl_xor(part, off, 64);
  __syncthreads();
  if (lane == 0) red[wv] = part;
  __syncthreads();
  if (tid == 0) {
    float tot = clampf(red[0] + red[1] + red[2] + red[3] + bfc[0], 30.f);
    float o = sigf(tot);
    if (isf32) ((float*)dout)[65536 + b] = o;
    else       ((u16*)dout)[65536 + b] = f2b(o);
  }
}

// ---------------------------------------------------------------------------
extern "C" void kernel_launch(void* const* d_in, const int* in_sizes, int n_in,
                              void* d_out, int out_size, void* d_ws, size_t ws_size,
                              hipStream_t stream) {
  const int* x_index = (const int*)d_in[0];
  const void* embed = d_in[1];
  const void* Wih0 = d_in[2];
  const void* Whh0 = d_in[3];
  const void* bih0 = d_in[4];
  const void* bhh0 = d_in[5];
  const void* Wih1 = d_in[6];
  const void* Whh1 = d_in[7];
  const void* bih1 = d_in[8];
  const void* bhh1 = d_in[9];
  const void* W1 = d_in[10];
  const void* b1 = d_in[11];
  const void* W2 = d_in[12];
  const void* b2 = d_in[13];
  const void* Wf = d_in[14];
  const void* bfv = d_in[15];

  char* ws = (char*)d_ws;
  size_t off = 0;
  auto alloc = [&](size_t bytes) -> char* {
    char* p = ws + off;
    off += (bytes + 255) & ~(size_t)255;
    return p;
  };
  u32* flags0    = (u32*)alloc(64 * 16 * 4);   // one flag per 64B line
  u32* flags1    = (u32*)alloc(64 * 16 * 4);
  u32* flag      = (u32*)alloc(256);
  float* biasR0  = (float*)alloc(2048 * 4);
  float* biasR1  = (float*)alloc(2048 * 4);
  float* part1   = (float*)alloc(64 * 256 * 4);
  float* e       = (float*)alloc(64 * 1024 * 4);
  float* b1c     = (float*)alloc(256 * 4);
  float* W2c     = (float*)alloc(256 * 4);
  float* b2c     = (float*)alloc(16);
  float* Wfc     = (float*)alloc(1024 * 4);
  float* bfc     = (float*)alloc(16);
  u16* W1c       = (u16*)alloc((size_t)256 * 1024 * 2);
  u16* Wcat0     = (u16*)alloc((size_t)2048 * 832 * 2);
  u16* Wcat1     = (u16*)alloc((size_t)2048 * 1024 * 2);
  u16* xT        = (u16*)alloc((size_t)65536 * 320 * 2);
  u16* h0sT      = (u16*)alloc((size_t)65536 * 512 * 2);
  u16* h1sT      = (u16*)alloc((size_t)65536 * 512 * 2);
  u16* part2     = (u16*)alloc((size_t)65536 * 256 * 2);
  (void)ws_size; (void)in_sizes; (void)n_in; (void)out_size;

  hipMemsetAsync(flags0, 0, 64 * 16 * 4 * 2, stream);  // flags0 + flags1
  hipLaunchKernelGGL(detect_kernel, dim3(1), dim3(256), 0, stream,
                     (const u16*)bih0, flag);
  hipLaunchKernelGGL(prep_kernel, dim3(512), dim3(256), 0, stream,
                     Wih0, Whh0, bih0, bhh0, Wih1, Whh1, bih1, bhh1,
                     W1, b1, W2, b2, Wf, bfv,
                     Wcat0, Wcat1, biasR0, biasR1,
                     W1c, b1c, W2c, b2c, Wfc, bfc, flag);
  hipLaunchKernelGGL(gather_kernel, dim3(16384), dim3(256), 0, stream,
                     x_index, embed, xT, flag);
  hipLaunchKernelGGL(lstm_fused, dim3(128), dim3(256), 0, stream,
                     xT, Wcat0, biasR0, Wcat1, biasR1,
                     h0sT, h1sT, flags0, flags1, 1024);
  hipLaunchKernelGGL(part1_kernel, dim3(64), dim3(256), 0, stream,
                     h1sT, W1c, b1c, part1);
  hipLaunchKernelGGL(gemm_hA, dim3(2, 512), dim3(256), 0, stream,
                     h1sT, W1c + 512, 1024, part2, 256, 512);
  hipLaunchKernelGGL(escore_kernel, dim3(16384), dim3(256), 0, stream,
                     part1, part2, W2c, b2c, e);
  hipLaunchKernelGGL(finish_kernel, dim3(64), dim3(256), 0, stream,
                     e, h1sT, Wfc, bfc, d_out, flag);
}